// Round 8
// baseline (240.380 us; speedup 1.0000x reference)
//
#include <hip/hip_runtime.h>
#include <math.h>

// rois [128, 256, 14, 14] fp32; BS=2, roinum=64, HID=128, C=256
constexpr int CIN  = 256;
constexpr int HID  = 128;
constexpr int P    = 196;   // 14*14
constexpr int PP   = 49;    // 7*7
constexpr int NQ   = 12544; // 64*196 per batch
constexpr int NKEY = 3136;  // 64*49  per batch

using f32x4 = __attribute__((ext_vector_type(4))) float;
using s16x8 = __attribute__((ext_vector_type(8))) short;
using s16x4 = __attribute__((ext_vector_type(4))) short;
using u32x2 = __attribute__((ext_vector_type(2))) unsigned int;
using u32x4 = __attribute__((ext_vector_type(4))) unsigned int;

// cheap bf16 round-half-up: (u + 0x8000) >> 16  (2 VALU ops)
__device__ __forceinline__ unsigned short f2bf(float x) {
    return (unsigned short)((__float_as_uint(x) + 0x8000u) >> 16);
}
// pack two f32 -> bf16x2 (low = a, high = b): 2 adds + 1 v_perm
__device__ __forceinline__ unsigned int pack_bf16(float a, float b) {
    const unsigned int ua = __float_as_uint(a) + 0x8000u;
    const unsigned int ub = __float_as_uint(b) + 0x8000u;
    return __builtin_amdgcn_perm(ua, ub, 0x03020706u);
}
__device__ __forceinline__ float bf2f(unsigned short s) {
    return __uint_as_float(((unsigned int)s) << 16);
}

// ============ prep: transpose+bf16 rois -> xq[m][c]; maxpool -> xkv; weights -> bf16
// grid 516 x 256 thr. Blocks 0..511: (ROI n = bx>>2, ch-group g = bx&3).
// Blocks 512..515: weight conversion (wq, wk, wv, wre).
__global__ __launch_bounds__(256) void prep_kernel(
    const float* __restrict__ rois,
    const float* __restrict__ wq, const float* __restrict__ wk,
    const float* __restrict__ wv, const float* __restrict__ wre,
    unsigned short* __restrict__ xq, unsigned short* __restrict__ xkv,
    unsigned short* __restrict__ wqb, unsigned short* __restrict__ wkb,
    unsigned short* __restrict__ wvb, unsigned short* __restrict__ wreb)
{
    const int bx = blockIdx.x;
    const int t  = threadIdx.x;

    if (bx >= 512) {
        const int which = bx - 512;
        const float* src = (which == 0) ? wq : (which == 1) ? wk : (which == 2) ? wv : wre;
        unsigned short* dst = (which == 0) ? wqb : (which == 1) ? wkb
                             : (which == 2) ? wvb : wreb;
        #pragma unroll 4
        for (int i = 0; i < 32; ++i) {
            const int idx = i * 256 + t;
            const float4 v = ((const float4*)src)[idx];
            u32x2 o;
            o[0] = pack_bf16(v.x, v.y);
            o[1] = pack_bf16(v.z, v.w);
            *(u32x2*)(dst + idx * 4) = o;
        }
        return;
    }

    const int n = bx >> 2;      // ROI index 0..127
    const int g = bx & 3;       // channel group (64 ch)
    const int b = n >> 6, r = n & 63;
    __shared__ float xT[196 * 68];   // [px][ch] fp32, pitch 68 (53 KB)

    const int c_loc = t >> 2;   // 0..63
    const int pq    = t & 3;

    // load 64 channels x 196 px, transposing into LDS
    const float4* row4 = (const float4*)(rois + ((size_t)n * CIN + g * 64 + c_loc) * P);
    #pragma unroll
    for (int j = 0; j < 13; ++j) {
        const int idx4 = pq + 4 * j;
        if (idx4 < 49) {
            const float4 v = row4[idx4];
            xT[(idx4 * 4 + 0) * 68 + c_loc] = v.x;
            xT[(idx4 * 4 + 1) * 68 + c_loc] = v.y;
            xT[(idx4 * 4 + 2) * 68 + c_loc] = v.z;
            xT[(idx4 * 4 + 3) * 68 + c_loc] = v.w;
        }
    }
    __syncthreads();

    // write xq: 196 px x 64 ch (bf16, 16B units)
    #pragma unroll
    for (int i = 0; i < 7; ++i) {
        const int u = i * 256 + t;
        if (u < 1568) {
            const int px = u >> 3, ch8 = (u & 7) * 8;
            u32x4 o;
            #pragma unroll
            for (int e = 0; e < 4; ++e)
                o[e] = pack_bf16(xT[px * 68 + ch8 + 2 * e], xT[px * 68 + ch8 + 2 * e + 1]);
            *(u32x4*)(xq + ((size_t)b * NQ + r * P + px) * CIN + g * 64 + ch8) = o;
        }
    }
    // maxpool 2x2 -> xkv: 49 pp x 64 ch
    #pragma unroll
    for (int i = 0; i < 2; ++i) {
        const int u = i * 256 + t;
        if (u < 392) {
            const int pp = u >> 3, ch8 = (u & 7) * 8;
            const int py = pp / 7, px_ = pp - py * 7;
            const int base00 = (py * 2) * 14 + px_ * 2;
            float mx[8];
            #pragma unroll
            for (int e = 0; e < 8; ++e) {
                const int c = ch8 + e;
                const float m0 = fmaxf(xT[(base00)      * 68 + c], xT[(base00 + 1)  * 68 + c]);
                const float m1 = fmaxf(xT[(base00 + 14) * 68 + c], xT[(base00 + 15) * 68 + c]);
                mx[e] = fmaxf(m0, m1);
            }
            u32x4 o;
            #pragma unroll
            for (int e = 0; e < 4; ++e) o[e] = pack_bf16(mx[2 * e], mx[2 * e + 1]);
            *(u32x4*)(xkv + ((size_t)b * NKEY + r * PP + pp) * CIN + g * 64 + ch8) = o;
        }
    }
}

// ============ fused Q/K/V MFMA GEMM (no LDS), V stored pre-transposed.
// grid 294: bx<196 -> Q (m=bx); 196..244 -> K (m=bx-196); 245..293 -> V (m=bx-245).
// Block 256 thr = 4 waves (2m x 2n), tile 128m x 128n. K contraction = 256.
__global__ __launch_bounds__(256) void gemm_fused_kernel(
    const unsigned short* __restrict__ xq, const unsigned short* __restrict__ xkv,
    const unsigned short* __restrict__ wqb, const unsigned short* __restrict__ wkb,
    const unsigned short* __restrict__ wvb,
    const float* __restrict__ bq, const float* __restrict__ bk, const float* __restrict__ bv,
    unsigned short* __restrict__ q, unsigned short* __restrict__ kmat,
    unsigned short* __restrict__ vt_g)
{
    const int bx = blockIdx.x;
    const unsigned short* x; const unsigned short* w; const float* bias;
    int m_blk, mode;   // 0=Q, 1=K, 2=V
    if (bx < 196)      { mode = 0; x = xq;  w = wqb; bias = bq; m_blk = bx; }
    else if (bx < 245) { mode = 1; x = xkv; w = wkb; bias = bk; m_blk = bx - 196; }
    else               { mode = 2; x = xkv; w = wvb; bias = bv; m_blk = bx - 245; }

    const int t = threadIdx.x;
    const int wid = t >> 6, lane = t & 63;
    const int quad = lane >> 4, c = lane & 15;
    const int m_base = m_blk * 128 + (wid & 1) * 64;
    const int n_base = (wid >> 1) * 64;

    f32x4 acc[4][4];
    #pragma unroll
    for (int i = 0; i < 4; ++i)
        #pragma unroll
        for (int j = 0; j < 4; ++j) acc[i][j] = (f32x4)(0.f);

    #pragma unroll
    for (int ks = 0; ks < 8; ++ks) {
        s16x8 af[4], bf[4];
        #pragma unroll
        for (int mt = 0; mt < 4; ++mt)
            af[mt] = *(const s16x8*)(x + (size_t)(m_base + mt * 16 + c) * CIN + ks * 32 + quad * 8);
        #pragma unroll
        for (int nt = 0; nt < 4; ++nt)
            bf[nt] = *(const s16x8*)(w + (size_t)(n_base + nt * 16 + c) * CIN + ks * 32 + quad * 8);
        #pragma unroll
        for (int mt = 0; mt < 4; ++mt)
            #pragma unroll
            for (int nt = 0; nt < 4; ++nt)
                acc[mt][nt] = __builtin_amdgcn_mfma_f32_16x16x32_bf16(af[mt], bf[nt], acc[mt][nt], 0, 0, 0);
    }

    if (mode <= 1) {
        unsigned short* out = (mode == 0) ? q : kmat;
        #pragma unroll
        for (int nt = 0; nt < 4; ++nt) {
            const float bv_ = bias[n_base + nt * 16 + c];
            #pragma unroll
            for (int mt = 0; mt < 4; ++mt)
                #pragma unroll
                for (int rr = 0; rr < 4; ++rr) {
                    const int m = m_base + mt * 16 + quad * 4 + rr;
                    out[(size_t)m * HID + n_base + nt * 16 + c] = f2bf(acc[mt][nt][rr] + bv_);
                }
        }
    } else {
        // V: store transposed vt_g[b][d][key]
        #pragma unroll
        for (int nt = 0; nt < 4; ++nt) {
            const int d = n_base + nt * 16 + c;
            const float bv_ = bias[d];
            #pragma unroll
            for (int mt = 0; mt < 4; ++mt)
                #pragma unroll
                for (int rr = 0; rr < 4; ++rr) {
                    const int key_g = m_base + mt * 16 + quad * 4 + rr;
                    const int bb = (key_g >= NKEY) ? 1 : 0;
                    const int kl = key_g - bb * NKEY;
                    vt_g[((size_t)bb * HID + d) * NKEY + kl] = f2bf(acc[mt][nt][rr] + bv_);
                }
        }
    }
}

// ============ MFMA attention: barrier-free, frags direct from global (L1/L2-hot).
// 64 q/wave, TK=32, S-way key split (runtime). Only LDS: wave-private P round-trip.
// grid (98, 2, S), block 128 = 2 waves. Partials bf16 per (split,batch) slice.
__global__ __launch_bounds__(128, 2) void attn_kernel(
    const unsigned short* __restrict__ q, const unsigned short* __restrict__ kmat,
    const unsigned short* __restrict__ vt_g,
    unsigned short* __restrict__ opart, float* __restrict__ lpart, int S)
{
    const int b    = blockIdx.y;
    const int s    = blockIdx.z;
    const int tid  = threadIdx.x;
    const int w    = tid >> 6;
    const int lane = tid & 63;
    const int quad = lane >> 4;
    const int c    = lane & 15;
    const int qb   = blockIdx.x * 128 + w * 64;

    // Ps pitch 72 shorts: b64 writes 4 lanes/slot, b128 reads 8 lanes/slot -> conflict-free.
    __shared__ unsigned short Ps[2][64 * 72];   // 18.4 KB total

    const unsigned short* qg = q    + (size_t)b * NQ   * HID;
    const unsigned short* kg = kmat + (size_t)b * NKEY * HID;
    const unsigned short* vt = vt_g + (size_t)b * HID  * NKEY;

    // Q fragments in registers for the whole kernel: B[n=q=c][k=d=quad*8+j]
    s16x8 qf[4][4];
    #pragma unroll
    for (int nt = 0; nt < 4; ++nt)
        #pragma unroll
        for (int ks = 0; ks < 4; ++ks)
            qf[nt][ks] = *(const s16x8*)(qg + (size_t)(qb + nt * 16 + c) * HID + ks * 32 + quad * 8);

    f32x4 Ob[4][8];
    #pragma unroll
    for (int nt = 0; nt < 4; ++nt)
        #pragma unroll
        for (int nd = 0; nd < 8; ++nd) Ob[nt][nd] = (f32x4)(0.f);
    float l[4] = {0.f, 0.f, 0.f, 0.f};

    const int kt0 = (98 * s) / S;
    const int kt1 = (98 * (s + 1)) / S;

    for (int kt = kt0; kt < kt1; ++kt) {
        const int kb = kt * 32;

        // ---- S^T = K.Q^T : A-frags straight from global (L1/L2-hot).
        f32x4 st[2][4];
        #pragma unroll
        for (int mt = 0; mt < 2; ++mt)
            #pragma unroll
            for (int nt = 0; nt < 4; ++nt) st[mt][nt] = (f32x4)(0.f);
        #pragma unroll
        for (int mt = 0; mt < 2; ++mt) {
            s16x8 kf[4];
            #pragma unroll
            for (int ks = 0; ks < 4; ++ks)
                kf[ks] = *(const s16x8*)(kg + (size_t)(kb + mt * 16 + c) * HID + ks * 32 + quad * 8);
            #pragma unroll
            for (int ks = 0; ks < 4; ++ks)
                #pragma unroll
                for (int nt = 0; nt < 4; ++nt)
                    st[mt][nt] = __builtin_amdgcn_mfma_f32_16x16x32_bf16(kf[ks], qf[nt][ks], st[mt][nt], 0, 0, 0);
        }

        // ---- exp (no max: scores bounded, fp32-safe), perm-pack -> Ps[q][key]
        #pragma unroll
        for (int mt = 0; mt < 2; ++mt) {
            #pragma unroll
            for (int nt = 0; nt < 4; ++nt) {
                const float e0 = __expf(st[mt][nt][0]);
                const float e1 = __expf(st[mt][nt][1]);
                const float e2 = __expf(st[mt][nt][2]);
                const float e3 = __expf(st[mt][nt][3]);
                l[nt] += (e0 + e1) + (e2 + e3);
                u32x2 pk;
                pk[0] = pack_bf16(e0, e1);
                pk[1] = pack_bf16(e2, e3);
                *(u32x2*)&Ps[w][(nt * 16 + c) * 72 + mt * 16 + quad * 4] = pk;
            }
        }
        // wave-private P: intra-wave DS ordering suffices (no barrier anywhere).

        // ---- O += P.V : A=P from LDS, B=Vt straight from global.
        s16x8 pf[4];
        #pragma unroll
        for (int nt = 0; nt < 4; ++nt)
            pf[nt] = *(const s16x8*)&Ps[w][(nt * 16 + c) * 72 + quad * 8];
        #pragma unroll
        for (int g2 = 0; g2 < 2; ++g2) {
            s16x8 vf[4];
            #pragma unroll
            for (int dd = 0; dd < 4; ++dd)
                vf[dd] = *(const s16x8*)(vt + (size_t)((g2 * 4 + dd) * 16 + c) * NKEY + kb + quad * 8);
            #pragma unroll
            for (int dd = 0; dd < 4; ++dd)
                #pragma unroll
                for (int nt = 0; nt < 4; ++nt)
                    Ob[nt][g2 * 4 + dd] = __builtin_amdgcn_mfma_f32_16x16x32_bf16(pf[nt], vf[dd], Ob[nt][g2 * 4 + dd], 0, 0, 0);
        }
    }

    // epilogue: bf16 unnormalized partials
    unsigned short* Op = opart + (size_t)(s * 2 + b) * NQ * HID;
    #pragma unroll
    for (int nt = 0; nt < 4; ++nt) {
        #pragma unroll
        for (int nd = 0; nd < 8; ++nd) {
            #pragma unroll
            for (int rr = 0; rr < 4; ++rr) {
                const int qrow = qb + nt * 16 + quad * 4 + rr;
                Op[(size_t)qrow * HID + nd * 16 + c] = f2bf(Ob[nt][nd][rr]);
            }
        }
    }
    #pragma unroll
    for (int nt = 0; nt < 4; ++nt) {
        l[nt] += __shfl_xor(l[nt], 16, 64);
        l[nt] += __shfl_xor(l[nt], 32, 64);
    }
    if (quad == 0) {
        float* lp = lpart + (size_t)(s * 2 + b) * NQ;
        #pragma unroll
        for (int nt = 0; nt < 4; ++nt) lp[qb + nt * 16 + c] = l[nt];
    }
}

// ============ outproj: merge S bf16 slices + normalize, then out = rois + wre@y + bre
// grid 392, 256 thr = 4 waves; block tile 256o x 64m.
__global__ __launch_bounds__(256) void outproj_kernel(
    const float* __restrict__ rois,
    const unsigned short* __restrict__ opart, const float* __restrict__ lpart,
    const unsigned short* __restrict__ wreb, const float* __restrict__ bre,
    float* __restrict__ out, int S)
{
    const int t = threadIdx.x;
    const int wid = t >> 6, lane = t & 63;
    const int quad = lane >> 4, c = lane & 15;
    const int m0 = blockIdx.x * 64;                 // global m in [0, 25088)
    const int b  = (m0 >= NQ) ? 1 : 0;

    __shared__ unsigned short ys[64 * 136];         // merged y tile bf16 [m][k]

    // ---- stage merged y tile: 4 threads per m-row, 32 channels each
    {
        const int m_loc = t >> 2, kq = t & 3;
        const int q_local = (m0 + m_loc) - b * NQ;
        float lsum = 0.f;
        for (int sl = 0; sl < S; ++sl)
            lsum += lpart[(size_t)(sl * 2 + b) * NQ + q_local];
        const float invl = 1.0f / lsum;
        float a32[32];
        #pragma unroll
        for (int e = 0; e < 32; ++e) a32[e] = 0.f;
        for (int sl = 0; sl < S; ++sl) {
            #pragma unroll
            for (int ch = 0; ch < 4; ++ch) {
                const s16x8 v = *(const s16x8*)&opart[
                    ((size_t)(sl * 2 + b) * NQ + q_local) * HID + kq * 32 + ch * 8];
                #pragma unroll
                for (int e = 0; e < 8; ++e) a32[ch * 8 + e] += bf2f((unsigned short)v[e]);
            }
        }
        #pragma unroll
        for (int ch = 0; ch < 4; ++ch) {
            u32x4 o;
            #pragma unroll
            for (int e = 0; e < 4; ++e)
                o[e] = pack_bf16(a32[ch * 8 + 2 * e] * invl, a32[ch * 8 + 2 * e + 1] * invl);
            *(u32x4*)&ys[m_loc * 136 + kq * 32 + ch * 8] = o;
        }
    }
    __syncthreads();

    // ---- A-frags (wre rows = this wave's 64 o)
    const int o_base = wid * 64;
    s16x8 af[4][4];
    #pragma unroll
    for (int mt = 0; mt < 4; ++mt)
        #pragma unroll
        for (int ks = 0; ks < 4; ++ks)
            af[mt][ks] = *(const s16x8*)(wreb + (size_t)(o_base + mt * 16 + c) * HID + ks * 32 + quad * 8);

    f32x4 acc[4][4];
    #pragma unroll
    for (int i = 0; i < 4; ++i)
        #pragma unroll
        for (int j = 0; j < 4; ++j) acc[i][j] = (f32x4)(0.f);

    #pragma unroll
    for (int ks = 0; ks < 4; ++ks) {
        s16x8 bf[4];
        #pragma unroll
        for (int nt = 0; nt < 4; ++nt)
            bf[nt] = *(const s16x8*)&ys[(nt * 16 + c) * 136 + ks * 32 + quad * 8];
        #pragma unroll
        for (int mt = 0; mt < 4; ++mt)
            #pragma unroll
            for (int nt = 0; nt < 4; ++nt)
                acc[mt][nt] = __builtin_amdgcn_mfma_f32_16x16x32_bf16(af[mt][ks], bf[nt], acc[mt][nt], 0, 0, 0);
    }

    // ---- epilogue: out[n][o][p] = rois + bre[o] + T[o][m]
    #pragma unroll
    for (int nt = 0; nt < 4; ++nt) {
        const int m_g = m0 + nt * 16 + c;
        const int mm  = m_g - b * NQ;
        const int r_roi = mm / 196;
        const int p     = mm - r_roi * 196;
        const int n_img = b * 64 + r_roi;
        const size_t base = ((size_t)n_img * CIN) * P + p;
        #pragma unroll
        for (int mt = 0; mt < 4; ++mt) {
            #pragma unroll
            for (int rr = 0; rr < 4; ++rr) {
                const int o = o_base + mt * 16 + quad * 4 + rr;
                out[base + (size_t)o * P] = rois[base + (size_t)o * P] + bre[o] + acc[mt][nt][rr];
            }
        }
    }
}

extern "C" void kernel_launch(void* const* d_in, const int* in_sizes, int n_in,
                              void* d_out, int out_size, void* d_ws, size_t ws_size,
                              hipStream_t stream)
{
    (void)in_sizes; (void)n_in; (void)out_size;
    const float* rois = (const float*)d_in[0];
    const float* wq  = (const float*)d_in[2];
    const float* bq  = (const float*)d_in[3];
    const float* wk  = (const float*)d_in[4];
    const float* bk  = (const float*)d_in[5];
    const float* wv  = (const float*)d_in[6];
    const float* bv  = (const float*)d_in[7];
    const float* wre = (const float*)d_in[8];
    const float* bre = (const float*)d_in[9];
    float* out = (float*)d_out;

    // Split count S chosen from workspace size (deterministic per process — graph-safe).
    // total(S) = 2*S*(3,211,264 + 50,176) + 9,699,328
    int S = (ws_size >= (size_t)74928128) ? 10
          : (ws_size >= (size_t)61882368) ? 8 : 5;

    char* ws = (char*)d_ws;
    const size_t opart_bytes = (size_t)2 * S * 3211264;   // 2S slices of NQ*HID bf16
    // opart at 0 aliases ONLY buffers fully consumed by gemm_fused before attn runs:
    //   xq [0, 12,845,056), xkv [12,845,056, 16,056,320), w* [16,056,320, 16,252,928).
    unsigned short* opart = (unsigned short*)(ws);
    unsigned short* xq    = (unsigned short*)(ws);
    unsigned short* xkv   = (unsigned short*)(ws + 12845056);
    unsigned short* wqb   = (unsigned short*)(ws + 16056320);   //  65,536
    unsigned short* wkb   = (unsigned short*)(ws + 16121856);   //  65,536
    unsigned short* wvb   = (unsigned short*)(ws + 16187392);   //  65,536
    // survivors live past opart:
    char* p = ws + opart_bytes;
    unsigned short* q     = (unsigned short*)(p);               // 6,422,528
    unsigned short* kmat  = (unsigned short*)(p + 6422528);     // 1,605,632
    unsigned short* vt_g  = (unsigned short*)(p + 8028160);     // 1,605,632
    float*          lpart = (float*)         (p + 9633792);     // 2S*50,176
    unsigned short* wreb  = (unsigned short*)(p + 9633792 + (size_t)2 * S * 50176);

    prep_kernel<<<dim3(516), 256, 0, stream>>>(rois, wq, wk, wv, wre,
                                               xq, xkv, wqb, wkb, wvb, wreb);
    gemm_fused_kernel<<<dim3(294), 256, 0, stream>>>(xq, xkv, wqb, wkb, wvb,
                                                     bq, bk, bv, q, kmat, vt_g);
    attn_kernel<<<dim3(98, 2, S), 128, 0, stream>>>(q, kmat, vt_g, opart, lpart, S);
    outproj_kernel<<<dim3(392), 256, 0, stream>>>(rois, opart, lpart, wreb, bre, out, S);
}